// Round 1
// baseline (690.150 us; speedup 1.0000x reference)
//
#include <hip/hip_runtime.h>
#include <hip/hip_bf16.h>

#define N_EXPERTS 8
#define EMB 1024
#define HID 2816
#define NTOK 4096
#define NSLOT (NTOK * 2)
#define TLIST NTOK

typedef float f32x4 __attribute__((ext_vector_type(4)));
typedef short short8 __attribute__((ext_vector_type(8)));

static __device__ __forceinline__ unsigned short f2bf(float v) {
    __hip_bfloat16 b = __float2bfloat16(v);
    return *reinterpret_cast<unsigned short*>(&b);
}

// ---------- weight transpose + fp32->bf16 convert: in [E][R][C] f32 -> out [E][C][R] bf16 ----------
__global__ __launch_bounds__(256) void transpose_cvt(const float* __restrict__ in,
                                                     unsigned short* __restrict__ out,
                                                     int R, int C) {
    __shared__ float tile[64][65];
    int e = blockIdx.z;
    int r0 = blockIdx.y * 64, c0 = blockIdx.x * 64;
    const float* src = in + (size_t)e * R * C;
    unsigned short* dst = out + (size_t)e * R * C;
    int tid = threadIdx.x;
#pragma unroll
    for (int i = 0; i < 16; ++i) {
        int lin = i * 256 + tid;
        int r = lin >> 6, c = lin & 63;
        tile[r][c] = src[(size_t)(r0 + r) * C + (c0 + c)];
    }
    __syncthreads();
#pragma unroll
    for (int i = 0; i < 16; ++i) {
        int lin = i * 256 + tid;
        int c = lin >> 6, r = lin & 63;
        dst[(size_t)(c0 + c) * R + (r0 + r)] = f2bf(tile[r][c]);
    }
}

// ---------- router: fp32 scores, top-2 softmax, build expert slot lists, emit x in bf16 ----------
__global__ __launch_bounds__(64) void router_kernel(const float* __restrict__ x,
                                                    const float* __restrict__ wr,
                                                    unsigned short* __restrict__ xbf,
                                                    int* __restrict__ counts,
                                                    int* __restrict__ lists,
                                                    float* __restrict__ gates) {
    int t = blockIdx.x, lane = threadIdx.x;
    const float* xr = x + (size_t)t * EMB;
    float acc[N_EXPERTS];
#pragma unroll
    for (int e = 0; e < N_EXPERTS; ++e) acc[e] = 0.f;
    for (int d = lane; d < EMB; d += 64) {
        float xv = xr[d];
        xbf[(size_t)t * EMB + d] = f2bf(xv);
        const float* w = wr + d * N_EXPERTS;
#pragma unroll
        for (int e = 0; e < N_EXPERTS; ++e) acc[e] += xv * w[e];
    }
#pragma unroll
    for (int off = 32; off; off >>= 1) {
#pragma unroll
        for (int e = 0; e < N_EXPERTS; ++e) acc[e] += __shfl_xor(acc[e], off, 64);
    }
    if (lane == 0) {
        int b0 = 0; float v0 = acc[0];
#pragma unroll
        for (int e = 1; e < N_EXPERTS; ++e) if (acc[e] > v0) { v0 = acc[e]; b0 = e; }
        int b1 = -1; float v1 = -1e30f;
#pragma unroll
        for (int e = 0; e < N_EXPERTS; ++e) if (e != b0 && acc[e] > v1) { v1 = acc[e]; b1 = e; }
        float g0 = 1.f / (1.f + expf(v1 - v0));
        float g1 = 1.f - g0;
        int p0 = atomicAdd(&counts[b0], 1);
        lists[b0 * TLIST + p0] = 2 * t;
        int p1 = atomicAdd(&counts[b1], 1);
        lists[b1 * TLIST + p1] = 2 * t + 1;
        gates[2 * t] = g0;
        gates[2 * t + 1] = g1;
    }
}

// ---------- GEMM1: per expert, h[slot] = silu(x@w1) * (x@w3), bf16 out ----------
// block tile 128(M) x 64(N) x 32(K); 4 waves in 2x2; wave tile 64x32 per matrix
__global__ __launch_bounds__(256) void gemm1_kernel(const unsigned short* __restrict__ xbf,
                                                    const unsigned short* __restrict__ w1T,
                                                    const unsigned short* __restrict__ w3T,
                                                    unsigned short* __restrict__ h,
                                                    const int* __restrict__ counts,
                                                    const int* __restrict__ lists) {
    int e = blockIdx.z;
    int cnt = counts[e];
    int rt = blockIdx.y;
    if (rt * 128 >= cnt) return;
    int n0 = blockIdx.x * 64;

    __shared__ unsigned short As[128 * 40];   // padded stride 40 to spread banks
    __shared__ unsigned short B1s[64 * 40];
    __shared__ unsigned short B3s[64 * 40];
    __shared__ int slotArr[128];

    int tid = threadIdx.x;
    if (tid < 128) {
        int r = rt * 128 + tid;
        slotArr[tid] = (r < cnt) ? lists[e * TLIST + r] : -1;
    }
    __syncthreads();

    // A staging: thread -> (row, 16-elem half)
    int arow = tid >> 1, ahalf = tid & 1;
    int slotA = slotArr[arow];
    int tokA = slotA >= 0 ? (slotA >> 1) : 0;
    const float4* aS = (const float4*)(xbf + (size_t)tokA * EMB + ahalf * 16);
    float4* aDst = (float4*)&As[arow * 40 + ahalf * 16];

    // B staging: threads 0-127 -> B1 rows, 128-255 -> B3 rows
    int bmat = tid >> 7;
    int brow = (tid & 127) >> 1, bhalf = tid & 1;
    const unsigned short* wT = bmat ? w3T : w1T;
    const float4* bS = (const float4*)(wT + ((size_t)e * HID + n0 + brow) * EMB + bhalf * 16);
    float4* bDst = (float4*)((bmat ? B3s : B1s) + brow * 40 + bhalf * 16);

    int lane = tid & 63, wid = tid >> 6;
    int wr = wid >> 1, wc = wid & 1;
    int lrow = lane & 15, quad = lane >> 4;

    f32x4 zero4 = {0.f, 0.f, 0.f, 0.f};
    f32x4 acc1[4][2], acc3[4][2];
#pragma unroll
    for (int mt = 0; mt < 4; ++mt)
#pragma unroll
        for (int nt = 0; nt < 2; ++nt) { acc1[mt][nt] = zero4; acc3[mt][nt] = zero4; }

    float4 aR0 = aS[0], aR1 = aS[1];
    float4 bR0 = bS[0], bR1 = bS[1];

    const int KT = EMB / 32;
    for (int kt = 0; kt < KT; ++kt) {
        __syncthreads();
        aDst[0] = aR0; aDst[1] = aR1;
        bDst[0] = bR0; bDst[1] = bR1;
        __syncthreads();
        if (kt + 1 < KT) {
            int o = (kt + 1) * 4;
            aR0 = aS[o]; aR1 = aS[o + 1];
            bR0 = bS[o]; bR1 = bS[o + 1];
        }
        short8 af[4], b1f[2], b3f[2];
#pragma unroll
        for (int mt = 0; mt < 4; ++mt)
            af[mt] = *(const short8*)&As[(wr * 64 + mt * 16 + lrow) * 40 + quad * 8];
#pragma unroll
        for (int nt = 0; nt < 2; ++nt) {
            b1f[nt] = *(const short8*)&B1s[(wc * 32 + nt * 16 + lrow) * 40 + quad * 8];
            b3f[nt] = *(const short8*)&B3s[(wc * 32 + nt * 16 + lrow) * 40 + quad * 8];
        }
#pragma unroll
        for (int mt = 0; mt < 4; ++mt)
#pragma unroll
            for (int nt = 0; nt < 2; ++nt) {
                acc1[mt][nt] = __builtin_amdgcn_mfma_f32_16x16x32_bf16(af[mt], b1f[nt], acc1[mt][nt], 0, 0, 0);
                acc3[mt][nt] = __builtin_amdgcn_mfma_f32_16x16x32_bf16(af[mt], b3f[nt], acc3[mt][nt], 0, 0, 0);
            }
    }

    // epilogue: silu(a1)*a3 -> h[slot][col] bf16
#pragma unroll
    for (int mt = 0; mt < 4; ++mt) {
#pragma unroll
        for (int i = 0; i < 4; ++i) {
            int r = wr * 64 + mt * 16 + quad * 4 + i;
            int slot = slotArr[r];
            if (slot < 0) continue;
#pragma unroll
            for (int nt = 0; nt < 2; ++nt) {
                float v1 = acc1[mt][nt][i];
                float v3 = acc3[mt][nt][i];
                float hv = v1 / (1.f + __expf(-v1)) * v3;
                int c = n0 + wc * 32 + nt * 16 + lrow;
                h[(size_t)slot * HID + c] = f2bf(hv);
            }
        }
    }
}

// ---------- GEMM2: y[t] += gate[slot] * h[slot] @ w2  (atomic scatter) ----------
__global__ __launch_bounds__(256) void gemm2_kernel(const unsigned short* __restrict__ h,
                                                    const unsigned short* __restrict__ w2T,
                                                    float* __restrict__ out,
                                                    const int* __restrict__ counts,
                                                    const int* __restrict__ lists,
                                                    const float* __restrict__ gates) {
    int e = blockIdx.z;
    int cnt = counts[e];
    int rt = blockIdx.y;
    if (rt * 128 >= cnt) return;
    int n0 = blockIdx.x * 64;

    __shared__ unsigned short As[128 * 40];
    __shared__ unsigned short Bs[64 * 40];
    __shared__ int slotArr[128];

    int tid = threadIdx.x;
    if (tid < 128) {
        int r = rt * 128 + tid;
        slotArr[tid] = (r < cnt) ? lists[e * TLIST + r] : -1;
    }
    __syncthreads();

    int arow = tid >> 1, ahalf = tid & 1;
    int slotA = slotArr[arow];
    int rowA = slotA >= 0 ? slotA : 0;
    const float4* aS = (const float4*)(h + (size_t)rowA * HID + ahalf * 16);
    float4* aDst = (float4*)&As[arow * 40 + ahalf * 16];

    bool doB = tid < 128;
    int brow = (tid & 127) >> 1, bhalf = tid & 1;
    const float4* bS = (const float4*)(w2T + ((size_t)e * EMB + n0 + brow) * HID + bhalf * 16);
    float4* bDst = (float4*)(Bs + brow * 40 + bhalf * 16);

    int lane = tid & 63, wid = tid >> 6;
    int wr = wid >> 1, wc = wid & 1;
    int lrow = lane & 15, quad = lane >> 4;

    f32x4 zero4 = {0.f, 0.f, 0.f, 0.f};
    f32x4 acc[4][2];
#pragma unroll
    for (int mt = 0; mt < 4; ++mt)
#pragma unroll
        for (int nt = 0; nt < 2; ++nt) acc[mt][nt] = zero4;

    float4 aR0 = aS[0], aR1 = aS[1];
    float4 bR0, bR1;
    if (doB) { bR0 = bS[0]; bR1 = bS[1]; }

    const int KT = HID / 32;
    for (int kt = 0; kt < KT; ++kt) {
        __syncthreads();
        aDst[0] = aR0; aDst[1] = aR1;
        if (doB) { bDst[0] = bR0; bDst[1] = bR1; }
        __syncthreads();
        if (kt + 1 < KT) {
            int o = (kt + 1) * 4;
            aR0 = aS[o]; aR1 = aS[o + 1];
            if (doB) { bR0 = bS[o]; bR1 = bS[o + 1]; }
        }
        short8 af[4], bf[2];
#pragma unroll
        for (int mt = 0; mt < 4; ++mt)
            af[mt] = *(const short8*)&As[(wr * 64 + mt * 16 + lrow) * 40 + quad * 8];
#pragma unroll
        for (int nt = 0; nt < 2; ++nt)
            bf[nt] = *(const short8*)&Bs[(wc * 32 + nt * 16 + lrow) * 40 + quad * 8];
#pragma unroll
        for (int mt = 0; mt < 4; ++mt)
#pragma unroll
            for (int nt = 0; nt < 2; ++nt)
                acc[mt][nt] = __builtin_amdgcn_mfma_f32_16x16x32_bf16(af[mt], bf[nt], acc[mt][nt], 0, 0, 0);
    }

#pragma unroll
    for (int mt = 0; mt < 4; ++mt) {
#pragma unroll
        for (int i = 0; i < 4; ++i) {
            int r = wr * 64 + mt * 16 + quad * 4 + i;
            int slot = slotArr[r];
            if (slot < 0) continue;
            int t = slot >> 1;
            float g = gates[slot];
#pragma unroll
            for (int nt = 0; nt < 2; ++nt) {
                int c = n0 + wc * 32 + nt * 16 + lrow;
                atomicAdd(&out[(size_t)t * EMB + c], g * acc[mt][nt][i]);
            }
        }
    }
}

extern "C" void kernel_launch(void* const* d_in, const int* in_sizes, int n_in,
                              void* d_out, int out_size, void* d_ws, size_t ws_size,
                              hipStream_t stream) {
    const float* x = (const float*)d_in[0];
    const float* wrout = (const float*)d_in[1];
    const float* w1 = (const float*)d_in[2];
    const float* w3 = (const float*)d_in[3];
    const float* w2 = (const float*)d_in[4];
    float* out = (float*)d_out;

    char* ws = (char*)d_ws;
    const size_t SW = (size_t)N_EXPERTS * EMB * HID * 2;  // 46,137,344 per weight matrix (bf16)
    const size_t SX = (size_t)NTOK * EMB * 2;             // 8,388,608
    const size_t SH = (size_t)NSLOT * HID * 2;            // 46,137,344
    const size_t NEEDED = 3 * SW + SX + SH + 256 + (size_t)N_EXPERTS * TLIST * 4 + (size_t)NSLOT * 4;
    if (ws_size < NEEDED) return;  // insufficient scratch; validation will flag

    unsigned short* w1T = (unsigned short*)(ws);
    unsigned short* w3T = (unsigned short*)(ws + SW);
    unsigned short* w2T = (unsigned short*)(ws + 2 * SW);
    unsigned short* xbf = (unsigned short*)(ws + 3 * SW);
    unsigned short* hbuf = (unsigned short*)(ws + 3 * SW + SX);
    char* meta = ws + 3 * SW + SX + SH;
    int* counts = (int*)meta;
    int* lists = (int*)(meta + 256);
    float* gates = (float*)(meta + 256 + (size_t)N_EXPERTS * TLIST * 4);

    hipMemsetAsync(counts, 0, 256, stream);
    hipMemsetAsync(d_out, 0, (size_t)out_size * sizeof(float), stream);

    // weights -> bf16, transposed to [N][K] so MFMA B-fragments are k-contiguous
    transpose_cvt<<<dim3(HID / 64, EMB / 64, N_EXPERTS), 256, 0, stream>>>(w1, w1T, EMB, HID);
    transpose_cvt<<<dim3(HID / 64, EMB / 64, N_EXPERTS), 256, 0, stream>>>(w3, w3T, EMB, HID);
    transpose_cvt<<<dim3(EMB / 64, HID / 64, N_EXPERTS), 256, 0, stream>>>(w2, w2T, HID, EMB);

    router_kernel<<<NTOK, 64, 0, stream>>>(x, wrout, xbf, counts, lists, gates);

    gemm1_kernel<<<dim3(HID / 64, NTOK / 128, N_EXPERTS), 256, 0, stream>>>(
        xbf, w1T, w3T, hbuf, counts, lists);
    gemm2_kernel<<<dim3(EMB / 64, NTOK / 128, N_EXPERTS), 256, 0, stream>>>(
        hbuf, w2T, out, counts, lists, gates);
}

// Round 3
// 534.437 us; speedup vs baseline: 1.2914x; 1.2914x over previous
//
#include <hip/hip_runtime.h>
#include <hip/hip_bf16.h>

#define N_EXPERTS 8
#define EMB 1024
#define HID 2816
#define NTOK 4096
#define NSLOT (NTOK * 2)
#define TLIST NTOK

typedef float f32x4 __attribute__((ext_vector_type(4)));
typedef short short8 __attribute__((ext_vector_type(8)));

static __device__ __forceinline__ unsigned short f2bf(float v) {
    __hip_bfloat16 b = __float2bfloat16(v);
    return *reinterpret_cast<unsigned short*>(&b);
}

// async global->LDS, 16B per lane. LDS dest = wave-uniform base + lane*16.
static __device__ __forceinline__ void ldst16(const unsigned short* g, unsigned short* l) {
    __builtin_amdgcn_global_load_lds(
        (const __attribute__((address_space(1))) unsigned int*)g,
        (__attribute__((address_space(3))) unsigned int*)l,
        16, 0, 0);
}

// ---------- weight transpose + fp32->bf16: in [E][R][C] f32 -> out [E][C][R] bf16 ----------
__global__ __launch_bounds__(256) void transpose_cvt(const float* __restrict__ in,
                                                     unsigned short* __restrict__ out,
                                                     int R, int C) {
    __shared__ unsigned short tile[64][68];
    int e = blockIdx.z;
    int r0 = blockIdx.y * 64, c0 = blockIdx.x * 64;
    const float* src = in + (size_t)e * R * C;
    unsigned short* dst = out + (size_t)e * R * C;
    int tid = threadIdx.x;
#pragma unroll
    for (int i = 0; i < 4; ++i) {
        int lin = i * 256 + tid;
        int r = lin >> 4, c4 = (lin & 15) * 4;
        float4 v = *(const float4*)&src[(size_t)(r0 + r) * C + c0 + c4];
        ushort4 b;
        b.x = f2bf(v.x); b.y = f2bf(v.y); b.z = f2bf(v.z); b.w = f2bf(v.w);
        *(ushort4*)&tile[r][c4] = b;
    }
    __syncthreads();
#pragma unroll
    for (int i = 0; i < 4; ++i) {
        int lin = i * 256 + tid;
        int c = lin >> 4, r4 = (lin & 15) * 4;
        ushort4 b;
        b.x = tile[r4 + 0][c]; b.y = tile[r4 + 1][c];
        b.z = tile[r4 + 2][c]; b.w = tile[r4 + 3][c];
        *(ushort4*)&dst[(size_t)(c0 + c) * R + r0 + r4] = b;
    }
}

// ---------- router: fp32 scores, top-2 softmax -> sel + gates; x -> bf16. NO atomics. ----------
__global__ __launch_bounds__(64) void router_kernel(const float* __restrict__ x,
                                                    const float* __restrict__ wr,
                                                    unsigned short* __restrict__ xbf,
                                                    int* __restrict__ sel,
                                                    float* __restrict__ gates) {
    int t = blockIdx.x, lane = threadIdx.x;
    const float* xr = x + (size_t)t * EMB;
    float acc[N_EXPERTS];
#pragma unroll
    for (int e = 0; e < N_EXPERTS; ++e) acc[e] = 0.f;
    for (int d = lane; d < EMB; d += 64) {
        float xv = xr[d];
        xbf[(size_t)t * EMB + d] = f2bf(xv);
        const float* w = wr + d * N_EXPERTS;
#pragma unroll
        for (int e = 0; e < N_EXPERTS; ++e) acc[e] += xv * w[e];
    }
#pragma unroll
    for (int off = 32; off; off >>= 1) {
#pragma unroll
        for (int e = 0; e < N_EXPERTS; ++e) acc[e] += __shfl_xor(acc[e], off, 64);
    }
    if (lane == 0) {
        int b0 = 0; float v0 = acc[0];
#pragma unroll
        for (int e = 1; e < N_EXPERTS; ++e) if (acc[e] > v0) { v0 = acc[e]; b0 = e; }
        int b1 = -1; float v1 = -1e30f;
#pragma unroll
        for (int e = 0; e < N_EXPERTS; ++e) if (e != b0 && acc[e] > v1) { v1 = acc[e]; b1 = e; }
        float g0 = 1.f / (1.f + expf(v1 - v0));
        float g1 = 1.f - g0;
        sel[t] = b0 | (b1 << 8);
        gates[2 * t] = g0;
        gates[2 * t + 1] = g1;
    }
}

// ---------- deterministic list build: one block per expert, ordered ballot compaction ----------
__global__ __launch_bounds__(256) void build_lists(const int* __restrict__ sel,
                                                   int* __restrict__ counts,
                                                   int* __restrict__ lists) {
    int e = blockIdx.x;
    int tid = threadIdx.x, lane = tid & 63, wid = tid >> 6;
    __shared__ int wsum[4];
    __shared__ int running;
    if (tid == 0) running = 0;
    __syncthreads();
    for (int base = 0; base < NTOK; base += 256) {
        int tok = base + tid;
        int s = sel[tok];
        int e0 = s & 0xff, e1 = (s >> 8) & 0xff;
        bool take = (e0 == e) || (e1 == e);
        int slot = (e0 == e) ? 2 * tok : 2 * tok + 1;
        unsigned long long b = __ballot(take);
        int lp = __popcll(b & ((1ull << lane) - 1ull));
        if (lane == 0) wsum[wid] = __popcll(b);
        __syncthreads();
        int off = running;
        for (int w = 0; w < wid; ++w) off += wsum[w];
        if (take) lists[e * TLIST + off + lp] = slot;
        __syncthreads();
        if (tid == 0) running += wsum[0] + wsum[1] + wsum[2] + wsum[3];
        __syncthreads();
    }
    if (tid == 0) counts[e] = running;
}

// ---------- GEMM1: h[slot] = silu(x@w1) * (x@w3), bf16 out ----------
__global__ __launch_bounds__(256) void gemm1_kernel(const unsigned short* __restrict__ xbf,
                                                    const unsigned short* __restrict__ w1T,
                                                    const unsigned short* __restrict__ w3T,
                                                    unsigned short* __restrict__ h,
                                                    const int* __restrict__ counts,
                                                    const int* __restrict__ lists) {
    int e = blockIdx.z;
    int cnt = counts[e];
    int rt = blockIdx.y;
    if (rt * 128 >= cnt) return;
    int n0 = blockIdx.x * 64;

    __shared__ unsigned short As[128 * 32];
    __shared__ unsigned short B1s[64 * 32];
    __shared__ unsigned short B3s[64 * 32];
    __shared__ int slotArr[128];

    int tid = threadIdx.x;
    if (tid < 128) {
        int r = rt * 128 + tid;
        slotArr[tid] = (r < cnt) ? lists[e * TLIST + r] : -1;
    }
    __syncthreads();

    int lane = tid & 63, wid = tid >> 6;
    int seg = lane >> 2, chunk = lane & 3;

    int rA0 = wid * 32 + seg, rA1 = wid * 32 + 16 + seg;
    int s0 = slotArr[rA0], s1 = slotArr[rA1];
    int t0 = s0 >= 0 ? (s0 >> 1) : 0, t1 = s1 >= 0 ? (s1 >> 1) : 0;
    const unsigned short* gA0 = xbf + (size_t)t0 * EMB + chunk * 8;
    const unsigned short* gA1 = xbf + (size_t)t1 * EMB + chunk * 8;
    int rB = n0 + wid * 16 + seg;
    const unsigned short* gB1 = w1T + ((size_t)e * HID + rB) * EMB + chunk * 8;
    const unsigned short* gB3 = w3T + ((size_t)e * HID + rB) * EMB + chunk * 8;
    unsigned short* lA0 = &As[wid * 1024];
    unsigned short* lA1 = &As[wid * 1024 + 512];
    unsigned short* lB1 = &B1s[wid * 512];
    unsigned short* lB3 = &B3s[wid * 512];

    int wr = wid >> 1, wc = wid & 1;
    int lrow = lane & 15, quad = lane >> 4;

    f32x4 zero4 = {0.f, 0.f, 0.f, 0.f};
    f32x4 acc1[4][2], acc3[4][2];
#pragma unroll
    for (int mt = 0; mt < 4; ++mt)
#pragma unroll
        for (int nt = 0; nt < 2; ++nt) { acc1[mt][nt] = zero4; acc3[mt][nt] = zero4; }

    const int KT = EMB / 32;
    for (int kt = 0; kt < KT; ++kt) {
        ldst16(gA0, lA0); ldst16(gA1, lA1);
        ldst16(gB1, lB1); ldst16(gB3, lB3);
        gA0 += 32; gA1 += 32; gB1 += 32; gB3 += 32;
        __builtin_amdgcn_s_waitcnt(0);   // explicit drain of global_load_lds before barrier
        __syncthreads();
        short8 af[4], b1f[2], b3f[2];
#pragma unroll
        for (int mt = 0; mt < 4; ++mt)
            af[mt] = *(const short8*)&As[(wr * 64 + mt * 16 + lrow) * 32 + quad * 8];
#pragma unroll
        for (int nt = 0; nt < 2; ++nt) {
            b1f[nt] = *(const short8*)&B1s[(wc * 32 + nt * 16 + lrow) * 32 + quad * 8];
            b3f[nt] = *(const short8*)&B3s[(wc * 32 + nt * 16 + lrow) * 32 + quad * 8];
        }
#pragma unroll
        for (int mt = 0; mt < 4; ++mt)
#pragma unroll
            for (int nt = 0; nt < 2; ++nt) {
                acc1[mt][nt] = __builtin_amdgcn_mfma_f32_16x16x32_bf16(af[mt], b1f[nt], acc1[mt][nt], 0, 0, 0);
                acc3[mt][nt] = __builtin_amdgcn_mfma_f32_16x16x32_bf16(af[mt], b3f[nt], acc3[mt][nt], 0, 0, 0);
            }
        __syncthreads();
    }

#pragma unroll
    for (int mt = 0; mt < 4; ++mt) {
#pragma unroll
        for (int i = 0; i < 4; ++i) {
            int r = wr * 64 + mt * 16 + quad * 4 + i;
            int slot = slotArr[r];
            if (slot < 0) continue;
#pragma unroll
            for (int nt = 0; nt < 2; ++nt) {
                float v1 = acc1[mt][nt][i];
                float v3 = acc3[mt][nt][i];
                float hv = v1 / (1.f + __expf(-v1)) * v3;
                int c = n0 + wc * 32 + nt * 16 + lrow;
                h[(size_t)slot * HID + c] = f2bf(hv);
            }
        }
    }
}

// ---------- GEMM2: oslot[slot] = gate[slot] * (h[slot] @ w2), plain fp32 stores ----------
__global__ __launch_bounds__(256) void gemm2_kernel(const unsigned short* __restrict__ h,
                                                    const unsigned short* __restrict__ w2T,
                                                    float* __restrict__ oslot,
                                                    const int* __restrict__ counts,
                                                    const int* __restrict__ lists,
                                                    const float* __restrict__ gates) {
    int e = blockIdx.z;
    int cnt = counts[e];
    int rt = blockIdx.y;
    if (rt * 128 >= cnt) return;
    int n0 = blockIdx.x * 128;

    __shared__ unsigned short As[128 * 32];
    __shared__ unsigned short Bs[128 * 32];
    __shared__ int slotArr[128];

    int tid = threadIdx.x;
    if (tid < 128) {
        int r = rt * 128 + tid;
        slotArr[tid] = (r < cnt) ? lists[e * TLIST + r] : -1;
    }
    __syncthreads();

    int lane = tid & 63, wid = tid >> 6;
    int seg = lane >> 2, chunk = lane & 3;

    int rA0 = wid * 32 + seg, rA1 = wid * 32 + 16 + seg;
    int s0 = slotArr[rA0], s1 = slotArr[rA1];
    const unsigned short* gA0 = h + (size_t)(s0 < 0 ? 0 : s0) * HID + chunk * 8;
    const unsigned short* gA1 = h + (size_t)(s1 < 0 ? 0 : s1) * HID + chunk * 8;
    int rB0 = n0 + wid * 32 + seg, rB1 = rB0 + 16;
    const unsigned short* gB0 = w2T + ((size_t)e * EMB + rB0) * HID + chunk * 8;
    const unsigned short* gB1 = w2T + ((size_t)e * EMB + rB1) * HID + chunk * 8;
    unsigned short* lA0 = &As[wid * 1024];
    unsigned short* lA1 = &As[wid * 1024 + 512];
    unsigned short* lB0 = &Bs[wid * 1024];
    unsigned short* lB1 = &Bs[wid * 1024 + 512];

    int wr = wid >> 1, wc = wid & 1;
    int lrow = lane & 15, quad = lane >> 4;

    f32x4 zero4 = {0.f, 0.f, 0.f, 0.f};
    f32x4 acc[4][4];
#pragma unroll
    for (int mt = 0; mt < 4; ++mt)
#pragma unroll
        for (int nt = 0; nt < 4; ++nt) acc[mt][nt] = zero4;

    const int KT = HID / 32;
    for (int kt = 0; kt < KT; ++kt) {
        ldst16(gA0, lA0); ldst16(gA1, lA1);
        ldst16(gB0, lB0); ldst16(gB1, lB1);
        gA0 += 32; gA1 += 32; gB0 += 32; gB1 += 32;
        __builtin_amdgcn_s_waitcnt(0);
        __syncthreads();
        short8 af[4], bf[4];
#pragma unroll
        for (int mt = 0; mt < 4; ++mt)
            af[mt] = *(const short8*)&As[(wr * 64 + mt * 16 + lrow) * 32 + quad * 8];
#pragma unroll
        for (int nt = 0; nt < 4; ++nt)
            bf[nt] = *(const short8*)&Bs[(wc * 64 + nt * 16 + lrow) * 32 + quad * 8];
#pragma unroll
        for (int mt = 0; mt < 4; ++mt)
#pragma unroll
            for (int nt = 0; nt < 4; ++nt)
                acc[mt][nt] = __builtin_amdgcn_mfma_f32_16x16x32_bf16(af[mt], bf[nt], acc[mt][nt], 0, 0, 0);
        __syncthreads();
    }

#pragma unroll
    for (int mt = 0; mt < 4; ++mt) {
#pragma unroll
        for (int i = 0; i < 4; ++i) {
            int r = wr * 64 + mt * 16 + quad * 4 + i;
            int slot = slotArr[r];
            if (slot < 0) continue;
            float g = gates[slot];
#pragma unroll
            for (int nt = 0; nt < 4; ++nt) {
                int c = n0 + wc * 64 + nt * 16 + lrow;
                oslot[(size_t)slot * EMB + c] = g * acc[mt][nt][i];
            }
        }
    }
}

// ---------- combine: y[t] = oslot[2t] + oslot[2t+1] ----------
__global__ __launch_bounds__(256) void combine_kernel(const float* __restrict__ oslot,
                                                      float* __restrict__ out) {
    int gid = blockIdx.x * 256 + threadIdx.x;
    int t = gid / (EMB / 4);
    int r = gid % (EMB / 4);
    const float4* a = (const float4*)(oslot + (size_t)(2 * t) * EMB);
    const float4* b = (const float4*)(oslot + (size_t)(2 * t + 1) * EMB);
    float4 va = a[r], vb = b[r];
    float4 vo = {va.x + vb.x, va.y + vb.y, va.z + vb.z, va.w + vb.w};
    ((float4*)out)[gid] = vo;
}

extern "C" void kernel_launch(void* const* d_in, const int* in_sizes, int n_in,
                              void* d_out, int out_size, void* d_ws, size_t ws_size,
                              hipStream_t stream) {
    const float* x = (const float*)d_in[0];
    const float* wrout = (const float*)d_in[1];
    const float* w1 = (const float*)d_in[2];
    const float* w3 = (const float*)d_in[3];
    const float* w2 = (const float*)d_in[4];
    float* out = (float*)d_out;

    char* ws = (char*)d_ws;
    const size_t SW = (size_t)N_EXPERTS * EMB * HID * 2;
    const size_t SX = (size_t)NTOK * EMB * 2;
    const size_t SH = (size_t)NSLOT * HID * 2;
    const size_t SMETA = 256 + (size_t)N_EXPERTS * TLIST * 4 + (size_t)NSLOT * 4 + (size_t)NTOK * 4;
    const size_t NEEDED = 3 * SW + SX + SH + SMETA;
    if (ws_size < NEEDED) return;

    unsigned short* w1T = (unsigned short*)(ws);
    unsigned short* w3T = (unsigned short*)(ws + SW);
    unsigned short* w2T = (unsigned short*)(ws + 2 * SW);
    unsigned short* xbf = (unsigned short*)(ws + 3 * SW);
    unsigned short* hbuf = (unsigned short*)(ws + 3 * SW + SX);
    char* meta = ws + 3 * SW + SX + SH;
    int* counts = (int*)meta;
    int* lists = (int*)(meta + 256);
    float* gates = (float*)(meta + 256 + (size_t)N_EXPERTS * TLIST * 4);
    int* sel = (int*)(meta + 256 + (size_t)N_EXPERTS * TLIST * 4 + (size_t)NSLOT * 4);
    // oslot (NSLOT*EMB fp32 = 33.5 MB) overlays w1T (dead after gemm1)
    float* oslot = (float*)(ws);

    transpose_cvt<<<dim3(HID / 64, EMB / 64, N_EXPERTS), 256, 0, stream>>>(w1, w1T, EMB, HID);
    transpose_cvt<<<dim3(HID / 64, EMB / 64, N_EXPERTS), 256, 0, stream>>>(w3, w3T, EMB, HID);
    transpose_cvt<<<dim3(EMB / 64, HID / 64, N_EXPERTS), 256, 0, stream>>>(w2, w2T, HID, EMB);

    router_kernel<<<NTOK, 64, 0, stream>>>(x, wrout, xbf, sel, gates);
    build_lists<<<N_EXPERTS, 256, 0, stream>>>(sel, counts, lists);

    gemm1_kernel<<<dim3(HID / 64, NTOK / 128, N_EXPERTS), 256, 0, stream>>>(
        xbf, w1T, w3T, hbuf, counts, lists);
    gemm2_kernel<<<dim3(EMB / 128, NTOK / 128, N_EXPERTS), 256, 0, stream>>>(
        hbuf, w2T, oslot, counts, lists, gates);
    combine_kernel<<<NTOK * EMB / 4 / 256, 256, 0, stream>>>(oslot, out);
}